// Round 14
// baseline (315.935 us; speedup 1.0000x reference)
//
#include <hip/hip_runtime.h>
#include <math.h>

typedef unsigned short ushort_t;
typedef __attribute__((ext_vector_type(8))) short bf16x8;
typedef __attribute__((ext_vector_type(4))) float f32x4;

__device__ __forceinline__ ushort_t f2bf(float f) {
  unsigned u = __float_as_uint(f);
  unsigned r = (u + 0x7FFF + ((u >> 16) & 1)) >> 16;  // RNE
  return (ushort_t)r;
}
__device__ __forceinline__ float bf2f(ushort_t u) {
  return __uint_as_float(((unsigned)u) << 16);
}
__device__ __forceinline__ float bflo(unsigned w) { return __uint_as_float(w << 16); }
__device__ __forceinline__ float bfhi(unsigned w) { return __uint_as_float(w & 0xffff0000u); }

__device__ __forceinline__ void gload_lds16(const void* g, void* l) {
  __builtin_amdgcn_global_load_lds(
      (const __attribute__((address_space(1))) void*)g,
      (__attribute__((address_space(3))) void*)l, 16, 0, 0);
}

#define PIPE_BAR(N)                                          \
  do {                                                       \
    asm volatile("s_waitcnt vmcnt(" #N ")" ::: "memory");    \
    __builtin_amdgcn_s_barrier();                            \
    asm volatile("" ::: "memory");                           \
  } while (0)

// counted wait: waves 0-3 issue 5 staging loads/phase, waves 4-7 issue 4
#define WAITC(n5, n4)                                        \
  do {                                                       \
    if (wlow) asm volatile("s_waitcnt vmcnt(" #n5 ")" ::: "memory"); \
    else      asm volatile("s_waitcnt vmcnt(" #n4 ")" ::: "memory"); \
    __builtin_amdgcn_s_barrier();                            \
    asm volatile("" ::: "memory");                           \
  } while (0)

// ---------------------------------------------------------------- CSR
__global__ void count_edges_k(const int* __restrict__ dst, int E, int* __restrict__ cnt) {
  int i = blockIdx.x * blockDim.x + threadIdx.x;
  if (i < E) atomicAdd(&cnt[dst[i]], 1);
}

// exclusive scan via wave shuffles; writes indptr AND cursor
__global__ void scan_k(const int* __restrict__ cnt, int* __restrict__ indptr,
                       int* __restrict__ cursor, int n) {
  __shared__ int wsum[16];
  __shared__ int carry_s;
  const int t = threadIdx.x, lane = t & 63, w = t >> 6;
  if (t == 0) carry_s = 0;
  __syncthreads();
  for (int base = 0; base < n; base += 1024) {
    int i = base + t;
    int v = (i < n) ? cnt[i] : 0;
    int x = v;
#pragma unroll
    for (int off = 1; off < 64; off <<= 1) {
      int y = __shfl_up(x, off);
      if (lane >= off) x += y;
    }
    if (lane == 63) wsum[w] = x;
    __syncthreads();
    if (w == 0 && lane < 16) {
      int y = wsum[lane];
#pragma unroll
      for (int off = 1; off < 16; off <<= 1) {
        int z = __shfl_up(y, off);
        if (lane >= off) y += z;
      }
      wsum[lane] = y;
    }
    __syncthreads();
    int woff = (w == 0) ? 0 : wsum[w - 1];
    int carry = carry_s;
    int incl = x + woff + carry;
    if (i < n) { indptr[i] = incl - v; cursor[i] = incl - v; }
    __syncthreads();
    if (t == 1023) carry_s = incl;
    __syncthreads();
  }
  if (threadIdx.x == 0) indptr[n] = carry_s;
}

__global__ void scatter_k(const int* __restrict__ src, const int* __restrict__ dst, int E, int n,
                          int* __restrict__ cursor, int* __restrict__ esrc) {
  int i = blockIdx.x * blockDim.x + threadIdx.x;
  if (i < E) {
    int p = atomicAdd(&cursor[dst[i]], 1);
    esrc[p] = src[i];
  } else if (i < E + n) {
    int node = i - E;
    int p = atomicAdd(&cursor[node], 1);
    esrc[p] = node;
  }
}

// ---------------------------------------------------------------- merged prep kernel (+init)
__device__ void transpose_dual_body(const float* __restrict__ Wa, int Na,
                                    const float* __restrict__ Wb, int Nb,
                                    int K, ushort_t* __restrict__ dst,
                                    int bxi, int byi, float (*tile)[33]) {
  const int bx = bxi * 32, by = byi * 32;
  const int tx = threadIdx.x & 31, ty = threadIdx.x >> 5;
  const bool isB = bx >= Na;
  const float* W = isB ? Wb : Wa;
  const int Nw = isB ? Nb : Na;
  const int nc = bx - (isB ? Na : 0) + tx;
  for (int i = ty; i < 32; i += 8)
    tile[i][tx] = W[(size_t)(by + i) * Nw + nc];
  __syncthreads();
  for (int i = ty; i < 32; i += 8)
    dst[(size_t)(bx + i) * K + by + tx] = f2bf(tile[tx][i]);
}

__global__ __launch_bounds__(256) void prep_k(const float* __restrict__ x, ushort_t* __restrict__ x_bf, int n4,
                                              const float* __restrict__ W1, const float* __restrict__ l1W, ushort_t* __restrict__ W1cat,
                                              const float* __restrict__ W2, const float* __restrict__ l2W, ushort_t* __restrict__ W2cat,
                                              const float* __restrict__ W3, const float* __restrict__ l3W, ushort_t* __restrict__ W3cat,
                                              const float* __restrict__ a3s, const float* __restrict__ a3d,
                                              int* __restrict__ cursor, int nN, float* __restrict__ z, int nz) {
  __shared__ float tile[32][33];
  const int b = blockIdx.x, t = threadIdx.x;
  if (b < 1250) {
    int i = b * 256 + t;
    if (i < n4) {
      float4 v = ((const float4*)x)[i];
      ushort_t* p = x_bf + i * 4;
      p[0] = f2bf(v.x); p[1] = f2bf(v.y); p[2] = f2bf(v.z); p[3] = f2bf(v.w);
    }
  } else if (b < 1506) {
    int lo = b - 1250;  // (64,4)
    transpose_dual_body(W1, 1024, l1W, 1024, 128, W1cat, lo % 64, lo / 64, tile);
  } else if (b < 3554) {
    int lo = b - 1506;  // (64,32)
    transpose_dual_body(W2, 1024, l2W, 1024, 1024, W2cat, lo % 64, lo / 64, tile);
  } else if (b < 4002) {
    int lo = b - 3554;  // (14,32)
    transpose_dual_body(W3, 384, l3W, 64, 1024, W3cat, lo % 14, lo / 14, tile);
  } else if (b < 4006) {
    int k = (b - 4002) * 256 + t;  // 0..1023
    const float* row = W3 + (size_t)k * 384;
    for (int hd = 0; hd < 6; ++hd) {
      float ss = 0.f, dd = 0.f;
      for (int c = 0; c < 64; ++c) {
        float w = row[hd * 64 + c];
        ss += w * a3s[hd * 64 + c];
        dd += w * a3d[hd * 64 + c];
      }
      W3cat[(size_t)(448 + hd) * 1024 + k] = f2bf(ss);
      W3cat[(size_t)(454 + hd) * 1024 + k] = f2bf(dd);
    }
    for (int j = 460; j < 512; ++j) W3cat[(size_t)j * 1024 + k] = 0;
  } else {
    int i = (b - 4006) * 256 + t;  // init: cursor=1 (self loop), zero logit accumulators
    if (i < nN) cursor[i] = 1;
    if (i < nz) z[i] = 0.f;
  }
}

// ---------------------------------------------------------------- gemm320 v4: 8-wave 5x8 frags
// BM=320 BN=256 BK=64; 512 thr / 8 waves (4 wm x 2 wn); wave tile 80x128, acc[5][8] (160 regs).
// Grid 8x32 = 256 blocks = 1 round. 4-deep half-phase ring: A[4][320][32], B[4][256][32]
// (144 KB); slot swizzle: LDS slot s of row r holds global 16B-slot s^((r>>1)&3).
template<int K, int HC, int SC, bool LOGITS>
__global__ __launch_bounds__(512, 2) void gemm320(const ushort_t* __restrict__ A,
                                                  const ushort_t* __restrict__ BT,
                                                  const float* __restrict__ skip_bias,
                                                  const float* __restrict__ a_src,
                                                  const float* __restrict__ a_dst,
                                                  float* __restrict__ sb,
                                                  float* __restrict__ db,
                                                  ushort_t* __restrict__ h_out,
                                                  ushort_t* __restrict__ skip_out,
                                                  int M) {
  __shared__ ushort_t As[4 * 320 * 32];  // 80 KB
  __shared__ ushort_t Bs[4 * 256 * 32];  // 64 KB
  const int gx = gridDim.x;
  const int nwg = gx * (int)gridDim.y;
  const int orig = blockIdx.y * gx + blockIdx.x;
  const int q = nwg >> 3, r = nwg & 7, xcd = orig & 7;
  const int wgid = (xcd < r ? xcd * (q + 1) : r * (q + 1) + (xcd - r) * q) + (orig >> 3);
  const int bm = (wgid / gx) * 320, bn = (wgid % gx) * 256;

  const int t = threadIdx.x, l = t & 63, wid = t >> 6;
  const bool wlow = (wid < 4);            // waves 0-3: 5 staging loads/phase; 4-7: 4
  const int wm = wid >> 1, wn = wid & 1;  // 4 x 2
  const int lr = l & 15, s4 = l >> 4;

  const int rA0 = t >> 2,          sA0 = (t & 3) ^ ((rA0 >> 1) & 3);
  const int rA1 = (t + 512) >> 2,  sA1 = ((t + 512) & 3) ^ ((rA1 >> 1) & 3);
  const int rA2 = (t + 1024) >> 2, sA2 = ((t + 1024) & 3) ^ ((rA2 >> 1) & 3);
  const size_t gA0 = (size_t)min(bm + rA0, M - 1) * K + sA0 * 8;
  const size_t gA1 = (size_t)min(bm + rA1, M - 1) * K + sA1 * 8;
  const size_t gA2 = (size_t)min(bm + rA2, M - 1) * K + sA2 * 8;
  const size_t gB0 = (size_t)(bn + rA0) * K + sA0 * 8;
  const size_t gB1 = (size_t)(bn + rA1) * K + sA1 * 8;
  const int dA0 = rA0 * 32 + (t & 3) * 8;
  const int dA1 = rA1 * 32 + ((t + 512) & 3) * 8;
  const int dA2 = rA2 * 32 + ((t + 1024) & 3) * 8;

  auto stage_half = [&](int p) {
    const int reg4 = p & 3;
    const int kc = p * 32;
    ushort_t* ar = &As[reg4 * (320 * 32)];
    ushort_t* br = &Bs[reg4 * (256 * 32)];
    gload_lds16(A + gA0 + kc, ar + dA0);
    gload_lds16(A + gA1 + kc, ar + dA1);
    if (t < 256) gload_lds16(A + gA2 + kc, ar + dA2);
    gload_lds16(BT + gB0 + kc, br + dA0);
    gload_lds16(BT + gB1 + kc, br + dA1);
  };

  int offA[5], offB[8];
#pragma unroll
  for (int m = 0; m < 5; ++m) {
    int row = wm * 80 + m * 16 + lr;
    offA[m] = row * 32 + ((s4 ^ ((row >> 1) & 3)) << 3);
  }
#pragma unroll
  for (int n = 0; n < 8; ++n) {
    int row = wn * 128 + n * 16 + lr;
    offB[n] = row * 32 + ((s4 ^ ((row >> 1) & 3)) << 3);
  }

  f32x4 acc[5][8] = {};

  auto body = [&](int p) {
    const int aB = (p & 3) * (320 * 32), bB = (p & 3) * (256 * 32);
    bf16x8 a[5], b[8];
#pragma unroll
    for (int m = 0; m < 5; ++m) a[m] = *(const bf16x8*)&As[aB + offA[m]];
#pragma unroll
    for (int n = 0; n < 8; ++n) b[n] = *(const bf16x8*)&Bs[bB + offB[n]];
    if (p + 3 < (K >> 5)) stage_half(p + 3);
    __builtin_amdgcn_s_setprio(1);
#pragma unroll
    for (int m = 0; m < 5; ++m)
#pragma unroll
      for (int n = 0; n < 8; ++n)
        acc[m][n] = __builtin_amdgcn_mfma_f32_16x16x32_bf16(a[m], b[n], acc[m][n], 0, 0, 0);
    __builtin_amdgcn_s_setprio(0);
  };

  constexpr int NP = K >> 5;
  stage_half(0); stage_half(1); stage_half(2);
  for (int p = 0; p < NP - 2; ++p) {
    WAITC(10, 8);
    body(p);
  }
  WAITC(5, 4); body(NP - 2);
  WAITC(0, 0); body(NP - 1);

  // ---- fused logits (L1/L2): wave's 128 cols lie within one 256-col head
  if (LOGITS && bn < HC) {
    const int head = bn >> 8;
    float as[8], ad[8];
#pragma unroll
    for (int n = 0; n < 8; ++n) {
      int c = (bn + wn * 128 + n * 16 + lr) & 255;
      as[n] = a_src[head * 256 + c];
      ad[n] = a_dst[head * 256 + c];
    }
#pragma unroll
    for (int mi = 0; mi < 5; ++mi) {
#pragma unroll
      for (int j = 0; j < 4; ++j) {
        float sp = 0.f, dp = 0.f;
#pragma unroll
        for (int n = 0; n < 8; ++n) { sp += acc[mi][n][j] * as[n]; dp += acc[mi][n][j] * ad[n]; }
#pragma unroll
        for (int off = 1; off <= 8; off <<= 1) {
          sp += __shfl_xor(sp, off);
          dp += __shfl_xor(dp, off);
        }
        if (lr == 0) {
          int row = bm + wm * 80 + mi * 16 + s4 * 4 + j;
          if (row < M) {
            atomicAdd(&sb[row * 4 + head], sp);
            atomicAdd(&db[row * 4 + head], dp);
          }
        }
      }
    }
  }

  // ---- epilogue: LDS transpose (padded) -> coalesced 32B row stores (2 passes of 32 rows)
  constexpr int EPS = 264;
  ushort_t* EP = As;
  const bool isH = (bn < HC);
#pragma unroll
  for (int mi = 0; mi < 5; ++mi) {
    __syncthreads();
#pragma unroll
    for (int n = 0; n < 8; ++n) {
      float bvn = isH ? 0.f : skip_bias[bn - HC + wn * 128 + n * 16 + lr];
#pragma unroll
      for (int j = 0; j < 4; ++j)
        EP[(wm * 16 + s4 * 4 + j) * EPS + wn * 128 + n * 16 + lr] = f2bf(acc[mi][n][j] + bvn);
    }
    __syncthreads();
#pragma unroll
    for (int rep = 0; rep < 2; ++rep) {
      const int r_l = (t >> 4) + rep * 32;
      const int c0 = (t & 15) * 16;
      const int grow = bm + (r_l >> 4) * 80 + mi * 16 + (r_l & 15);
      if (grow < M) {
        const ushort_t* srcp = &EP[r_l * EPS + c0];
        ushort_t* dst = isH ? &h_out[(size_t)grow * HC + bn + c0]
                            : &skip_out[(size_t)grow * SC + (bn - HC) + c0];
        *(uint4*)dst = *(const uint4*)srcp;
        *(uint4*)(dst + 8) = *(const uint4*)(srcp + 8);
      }
    }
  }
}

// ---------------------------------------------------------------- 128x128 ring GEMM (L3)
template<int NCT, int HC, int SC, bool SD_COLS>
__global__ __launch_bounds__(256) void gemm_fused(const ushort_t* __restrict__ A,
                                                  const ushort_t* __restrict__ BT,
                                                  const float* __restrict__ skip_bias,
                                                  float* __restrict__ sb,
                                                  float* __restrict__ db,
                                                  ushort_t* __restrict__ h_out,
                                                  float* __restrict__ skip_out,
                                                  int M, int K) {
  __shared__ ushort_t As[4][128 * 32];
  __shared__ ushort_t Bs[4][128 * 32];
  const int gx = gridDim.x;
  const int nwg = gx * (int)gridDim.y;
  const int orig = blockIdx.y * gx + blockIdx.x;
  const int q = nwg >> 3, r = nwg & 7, xcd = orig & 7;
  const int wgid = (xcd < r ? xcd * (q + 1) : r * (q + 1) + (xcd - r) * q) + (orig >> 3);
  const int bm = (wgid / gx) * 128, bn = (wgid % gx) * 128;

  const int t = threadIdx.x;
  const int l = t & 63, wid = t >> 6;
  const int wm = wid >> 1, wn = wid & 1;

  size_t goffA[2], goffB[2];
  for (int i = 0; i < 2; ++i) {
    int seg = wid * 2 + i;
    int row = seg * 16 + (l >> 2);
    int p = l & 3;
    int ls = p ^ ((row >> 1) & 3);
    int ga = min(bm + row, M - 1);
    int gb = min(bn + row, NCT - 1);
    goffA[i] = (size_t)ga * K + ls * 8;
    goffB[i] = (size_t)gb * K + ls * 8;
  }

  const int lr = l & 15, s = l >> 4;
  int raddrA[4], raddrB[4];
  for (int m = 0; m < 4; ++m) {
    int rowA = wm * 64 + m * 16 + lr;
    raddrA[m] = rowA * 32 + (s ^ ((rowA >> 1) & 3)) * 8;
    int rowB = wn * 64 + m * 16 + lr;
    raddrB[m] = rowB * 32 + (s ^ ((rowB >> 1) & 3)) * 8;
  }

  f32x4 acc[4][4] = {};
  auto stage = [&](int st) {
    int buf = st & 3;
    int k0 = st * 32;
    gload_lds16(A + goffA[0] + k0, &As[buf][(wid * 2 + 0) * 512]);
    gload_lds16(A + goffA[1] + k0, &As[buf][(wid * 2 + 1) * 512]);
    gload_lds16(BT + goffB[0] + k0, &Bs[buf][(wid * 2 + 0) * 512]);
    gload_lds16(BT + goffB[1] + k0, &Bs[buf][(wid * 2 + 1) * 512]);
  };
  auto body = [&](int st) {
    int buf = st & 3;
    bf16x8 a[4], b[4];
#pragma unroll
    for (int m = 0; m < 4; ++m) a[m] = *(const bf16x8*)&As[buf][raddrA[m]];
#pragma unroll
    for (int n = 0; n < 4; ++n) b[n] = *(const bf16x8*)&Bs[buf][raddrB[n]];
#pragma unroll
    for (int m = 0; m < 4; ++m)
#pragma unroll
      for (int n = 0; n < 4; ++n)
        acc[m][n] = __builtin_amdgcn_mfma_f32_16x16x32_bf16(a[m], b[n], acc[m][n], 0, 0, 0);
  };

  const int T = K >> 5;
  stage(0); stage(1); stage(2);
  int st = 0;
  for (; st < T - 3; ++st) {
    PIPE_BAR(8);
    body(st);
    stage(st + 3);
  }
  PIPE_BAR(8); body(T - 3);
  PIPE_BAR(4); body(T - 2);
  PIPE_BAR(0); body(T - 1);

#pragma unroll
  for (int n = 0; n < 4; ++n) {
    int col = bn + wn * 64 + n * 16 + lr;
    if (col >= HC + SC + (SD_COLS ? 12 : 0)) continue;
    const bool is_h = col < HC;
    const bool is_skip = !is_h && col < HC + SC;
    float bv = is_skip ? skip_bias[col - HC] : 0.f;
#pragma unroll
    for (int m = 0; m < 4; ++m) {
#pragma unroll
      for (int j = 0; j < 4; ++j) {
        int row = bm + wm * 64 + m * 16 + (l >> 4) * 4 + j;
        if (row >= M) continue;
        float v = acc[m][n][j] + bv;
        if (is_h) {
          h_out[(size_t)row * HC + col] = f2bf(v);
        } else if (is_skip) {
          skip_out[(size_t)row * SC + (col - HC)] = v;
        } else if (SD_COLS) {
          int jj = col - (HC + SC);
          if (jj < 6) sb[row * 6 + jj] = v;
          else        db[row * 6 + (jj - 6)] = v;
        }
      }
    }
  }
}

// ---------------------------------------------------------------- attn L1/L2: parity-split gather
template<bool ELU_OUT>
__global__ __launch_bounds__(256) void attn4_k(const ushort_t* __restrict__ hfeat,
                                               const float* __restrict__ sbuf,
                                               const float* __restrict__ dbuf,
                                               const int* __restrict__ indptr,
                                               const int* __restrict__ esrc,
                                               const float* __restrict__ bias,
                                               const ushort_t* __restrict__ skip,
                                               ushort_t* __restrict__ out) {
  constexpr int H = 4, F = 1024, CH = 64;
  __shared__ float m_l[H], invden_l[H], d_l[H];
  __shared__ float alpha_l[CH * H];
  __shared__ int src_l[CH];
  __shared__ float mrg[F];  // 4 KB parity-merge buffer

  const int node = blockIdx.x;
  const int t = threadIdx.x;
  const int beg = indptr[node];
  const int deg = indptr[node + 1] - beg;
  if (t < H) d_l[t] = dbuf[node * H + t];
  __syncthreads();

  const int wave = t >> 6, lane = t & 63;
  {
    const int hd = wave;
    const float dn = d_l[hd];
    float mx = -1e30f;
    for (int i = lane; i < deg; i += 64) {
      float e = sbuf[esrc[beg + i] * H + hd] + dn;
      e = fmaxf(e, 0.2f * e);
      mx = fmaxf(mx, e);
    }
    for (int off = 32; off; off >>= 1) mx = fmaxf(mx, __shfl_xor(mx, off));
    float den = 0.f;
    for (int i = lane; i < deg; i += 64) {
      float e = sbuf[esrc[beg + i] * H + hd] + dn;
      e = fmaxf(e, 0.2f * e);
      den += __expf(e - mx);
    }
    for (int off = 32; off; off >>= 1) den += __shfl_xor(den, off);
    if (lane == 0) { m_l[hd] = mx; invden_l[hd] = 1.f / den; }
  }
  __syncthreads();

  const int eo = t >> 7;
  const int tc = t & 127;
  const int c0 = tc * 8;
  const int myhead = tc >> 5;
  float acc[8] = {};
  for (int cb = 0; cb < deg; cb += CH) {
    const int ce = min(CH, deg - cb);
    if (t < ce * H) {
      int e_i = t >> 2, hd = t & 3;
      int se = esrc[beg + cb + e_i];
      if (hd == 0) src_l[e_i] = se;
      float e = sbuf[se * H + hd] + d_l[hd];
      e = fmaxf(e, 0.2f * e);
      alpha_l[e_i * H + hd] = __expf(e - m_l[hd]) * invden_l[hd];
    }
    __syncthreads();
    for (int e_i = eo; e_i < ce; e_i += 2) {
      int se = src_l[e_i];
      float al = alpha_l[e_i * H + myhead];
      uint4 v = *(const uint4*)(hfeat + (size_t)se * F + c0);
      acc[0] += al * bflo(v.x); acc[1] += al * bfhi(v.x);
      acc[2] += al * bflo(v.y); acc[3] += al * bfhi(v.y);
      acc[4] += al * bflo(v.z); acc[5] += al * bfhi(v.z);
      acc[6] += al * bflo(v.w); acc[7] += al * bfhi(v.w);
    }
    __syncthreads();
  }

  if (eo == 1) {
#pragma unroll
    for (int j = 0; j < 8; ++j) mrg[c0 + j] = acc[j];
  }
  __syncthreads();
  if (eo == 0) {
    uint4 sv = *(const uint4*)&skip[(size_t)node * F + c0];
    float sk[8] = {bflo(sv.x), bfhi(sv.x), bflo(sv.y), bfhi(sv.y),
                   bflo(sv.z), bfhi(sv.z), bflo(sv.w), bfhi(sv.w)};
    unsigned w[4];
#pragma unroll
    for (int p = 0; p < 4; ++p) {
      float x0 = acc[2 * p] + mrg[c0 + 2 * p] + bias[c0 + 2 * p] + sk[2 * p];
      float x1 = acc[2 * p + 1] + mrg[c0 + 2 * p + 1] + bias[c0 + 2 * p + 1] + sk[2 * p + 1];
      if (ELU_OUT) {
        x0 = x0 > 0.f ? x0 : __expf(x0) - 1.f;
        x1 = x1 > 0.f ? x1 : __expf(x1) - 1.f;
      }
      w[p] = (unsigned)f2bf(x0) | ((unsigned)f2bf(x1) << 16);
    }
    uint4 o; o.x = w[0]; o.y = w[1]; o.z = w[2]; o.w = w[3];
    *(uint4*)&out[(size_t)node * F + c0] = o;
  }
}

// ---------------------------------------------------------------- attn L3 (H=6, C=64, mean-heads)
// Parity-split gather: eo = t>>7, 96 threads/parity, 4 cols/thread via 8B uint2 loads.
// Parity sums merged in LDS; head-mean + bias + fp32 skip epilogue by t<64.
__global__ __launch_bounds__(256) void attn_mean_k(const ushort_t* __restrict__ hfeat,
                                                   const float* __restrict__ sbuf,
                                                   const float* __restrict__ dbuf,
                                                   const int* __restrict__ indptr,
                                                   const int* __restrict__ esrc,
                                                   const float* __restrict__ bias,
                                                   const float* __restrict__ skip,
                                                   float* __restrict__ out) {
  constexpr int H = 6, C = 64, F = 384, CH = 42;
  __shared__ float m_l[H], invden_l[H], d_l[H];
  __shared__ float alpha_l[CH * H];
  __shared__ int src_l[CH];
  __shared__ float accs[2 * F];  // parity sums (3 KB)

  const int node = blockIdx.x;
  const int t = threadIdx.x;
  const int beg = indptr[node];
  const int deg = indptr[node + 1] - beg;
  if (t < H) d_l[t] = dbuf[node * H + t];
  __syncthreads();

  const int wave = t >> 6, lane = t & 63;
  for (int hd = wave; hd < H; hd += 4) {
    const float dn = d_l[hd];
    float mx = -1e30f;
    for (int i = lane; i < deg; i += 64) {
      float e = sbuf[esrc[beg + i] * H + hd] + dn;
      e = fmaxf(e, 0.2f * e);
      mx = fmaxf(mx, e);
    }
    for (int off = 32; off; off >>= 1) mx = fmaxf(mx, __shfl_xor(mx, off));
    float den = 0.f;
    for (int i = lane; i < deg; i += 64) {
      float e = sbuf[esrc[beg + i] * H + hd] + dn;
      e = fmaxf(e, 0.2f * e);
      den += __expf(e - mx);
    }
    for (int off = 32; off; off >>= 1) den += __shfl_xor(den, off);
    if (lane == 0) { m_l[hd] = mx; invden_l[hd] = 1.f / den; }
  }
  __syncthreads();

  const int eo = t >> 7;       // edge parity
  const int tc = t & 127;      // active if tc < 96
  const int c0 = tc * 4;       // col base (0..380)
  const int myhead = c0 >> 6;  // c0/64
  float acc[4] = {};
  for (int cb = 0; cb < deg; cb += CH) {
    const int ce = min(CH, deg - cb);
    if (t < ce * H) {
      int e_i = t / H, hd = t % H;
      int se = esrc[beg + cb + e_i];
      if (hd == 0) src_l[e_i] = se;
      float e = sbuf[se * H + hd] + d_l[hd];
      e = fmaxf(e, 0.2f * e);
      alpha_l[e_i * H + hd] = __expf(e - m_l[hd]) * invden_l[hd];
    }
    __syncthreads();
    if (tc < 96) {
      for (int e_i = eo; e_i < ce; e_i += 2) {
        int se = src_l[e_i];
        float al = alpha_l[e_i * H + myhead];
        uint2 v = *(const uint2*)(hfeat + (size_t)se * F + c0);
        acc[0] += al * bflo(v.x); acc[1] += al * bfhi(v.x);
        acc[2] += al * bflo(v.y); acc[3] += al * bfhi(v.y);
      }
    }
    __syncthreads();
  }

  if (tc < 96) {
    float4 o; o.x = acc[0]; o.y = acc[1]; o.z = acc[2]; o.w = acc[3];
    *(float4*)&accs[eo * F + c0] = o;
  }
  __syncthreads();
  if (t < C) {
    float sum = 0.f;
#pragma unroll
    for (int hd = 0; hd < H; ++hd) sum += accs[hd * C + t] + accs[F + hd * C + t];
    out[(size_t)node * C + t] = sum * (1.f / (float)H) + bias[t] + skip[(size_t)node * C + t];
  }
}

// ---------------------------------------------------------------- launch
extern "C" void kernel_launch(void* const* d_in, const int* in_sizes, int n_in,
                              void* d_out, int out_size, void* d_ws, size_t ws_size,
                              hipStream_t stream) {
  const float* x      = (const float*)d_in[0];
  const int*   ei     = (const int*)d_in[1];
  const float* W1     = (const float*)d_in[2];
  const float* a1s    = (const float*)d_in[3];
  const float* a1d    = (const float*)d_in[4];
  const float* b1     = (const float*)d_in[5];
  const float* lin1W  = (const float*)d_in[6];
  const float* lin1b  = (const float*)d_in[7];
  const float* W2     = (const float*)d_in[8];
  const float* a2s    = (const float*)d_in[9];
  const float* a2d    = (const float*)d_in[10];
  const float* b2     = (const float*)d_in[11];
  const float* lin2W  = (const float*)d_in[12];
  const float* lin2b  = (const float*)d_in[13];
  const float* W3     = (const float*)d_in[14];
  const float* a3s    = (const float*)d_in[15];
  const float* a3d    = (const float*)d_in[16];
  const float* b3     = (const float*)d_in[17];
  const float* lin3W  = (const float*)d_in[18];
  const float* lin3b  = (const float*)d_in[19];

  const int N = in_sizes[0] / 128;
  const int E = in_sizes[1] / 2;
  const int* src = ei;
  const int* dst = ei + E;

  char* ws = (char*)d_ws;
  size_t off = 0;
  auto alloc = [&](size_t bytes) -> void* {
    void* p = ws + off;
    off += (bytes + 255) & ~(size_t)255;
    return p;
  };
  ushort_t* h_bf    = (ushort_t*)alloc((size_t)N * 1024 * 2);
  ushort_t* skip_bf = (ushort_t*)alloc((size_t)N * 1024 * 2);
  float*    skip3   = (float*)alloc((size_t)N * 64 * 4);
  ushort_t* act_bf  = (ushort_t*)alloc((size_t)N * 1024 * 2);
  ushort_t* x_bf    = (ushort_t*)alloc((size_t)N * 128 * 2);
  ushort_t* W1cat   = (ushort_t*)alloc((size_t)2048 * 128 * 2);
  ushort_t* W2cat   = (ushort_t*)alloc((size_t)2048 * 1024 * 2);
  ushort_t* W3cat   = (ushort_t*)alloc((size_t)512 * 1024 * 2);
  float*    sd12    = (float*)alloc((size_t)4 * N * 4 * 4);
  float*    sb1 = sd12, *db1 = sd12 + N * 4, *sb2 = sd12 + 2 * N * 4, *db2 = sd12 + 3 * N * 4;
  float*    sb3     = (float*)alloc((size_t)N * 6 * 4);
  float*    db3     = (float*)alloc((size_t)N * 6 * 4);
  int*      indptr  = (int*)alloc((size_t)(N + 1) * 4);
  int*      cursor  = (int*)alloc((size_t)N * 4);
  int*      esrc    = (int*)alloc((size_t)(E + N) * 4);

  const int n4 = N * 128 / 4;
  const int NZ = 4 * N * 4;
  const int initBlocks = (max(N, NZ) + 255) / 256;
  prep_k<<<4006 + initBlocks, 256, 0, stream>>>(x, x_bf, n4, W1, lin1W, W1cat, W2, lin2W, W2cat,
                                                W3, lin3W, W3cat, a3s, a3d, cursor, N, sd12, NZ);

  count_edges_k<<<(E + 255) / 256, 256, 0, stream>>>(dst, E, cursor);
  scan_k<<<1, 1024, 0, stream>>>(cursor, indptr, cursor, N);
  scatter_k<<<(E + N + 255) / 256, 256, 0, stream>>>(src, dst, E, N, cursor, esrc);

  const int MB  = (N + 127) / 128;
  const int MB3 = (N + 319) / 320;
  // ---- Layer 1 (K=128)
  gemm320<128, 1024, 1024, true><<<dim3(8, MB3), 512, 0, stream>>>(
      x_bf, W1cat, lin1b, a1s, a1d, sb1, db1, h_bf, skip_bf, N);
  attn4_k<true><<<N, 256, 0, stream>>>(h_bf, sb1, db1, indptr, esrc, b1, skip_bf, act_bf);
  // ---- Layer 2 (K=1024)
  gemm320<1024, 1024, 1024, true><<<dim3(8, MB3), 512, 0, stream>>>(
      act_bf, W2cat, lin2b, a2s, a2d, sb2, db2, h_bf, skip_bf, N);
  attn4_k<true><<<N, 256, 0, stream>>>(h_bf, sb2, db2, indptr, esrc, b2, skip_bf, act_bf);
  // ---- Layer 3 (128x128 ring; logits via folded cols 448..459)
  gemm_fused<512, 384, 64, true><<<dim3(4, MB), 256, 0, stream>>>(
      act_bf, W3cat, lin3b, sb3, db3, h_bf, skip3, N, 1024);
  attn_mean_k<<<N, 256, 0, stream>>>(h_bf, sb3, db3, indptr, esrc, b3, skip3, (float*)d_out);
}

// Round 15
// 309.493 us; speedup vs baseline: 1.0208x; 1.0208x over previous
//
#include <hip/hip_runtime.h>
#include <math.h>

typedef unsigned short ushort_t;
typedef __attribute__((ext_vector_type(8))) short bf16x8;
typedef __attribute__((ext_vector_type(4))) float f32x4;

__device__ __forceinline__ ushort_t f2bf(float f) {
  unsigned u = __float_as_uint(f);
  unsigned r = (u + 0x7FFF + ((u >> 16) & 1)) >> 16;  // RNE
  return (ushort_t)r;
}
__device__ __forceinline__ float bf2f(ushort_t u) {
  return __uint_as_float(((unsigned)u) << 16);
}
__device__ __forceinline__ float bflo(unsigned w) { return __uint_as_float(w << 16); }
__device__ __forceinline__ float bfhi(unsigned w) { return __uint_as_float(w & 0xffff0000u); }

__device__ __forceinline__ void gload_lds16(const void* g, void* l) {
  __builtin_amdgcn_global_load_lds(
      (const __attribute__((address_space(1))) void*)g,
      (__attribute__((address_space(3))) void*)l, 16, 0, 0);
}

#define PIPE_BAR(N)                                          \
  do {                                                       \
    asm volatile("s_waitcnt vmcnt(" #N ")" ::: "memory");    \
    __builtin_amdgcn_s_barrier();                            \
    asm volatile("" ::: "memory");                           \
  } while (0)

// counted wait: waves 0-3 issue 5 staging loads/phase, waves 4-7 issue 4
#define WAITC(n5, n4)                                        \
  do {                                                       \
    if (wlow) asm volatile("s_waitcnt vmcnt(" #n5 ")" ::: "memory"); \
    else      asm volatile("s_waitcnt vmcnt(" #n4 ")" ::: "memory"); \
    __builtin_amdgcn_s_barrier();                            \
    asm volatile("" ::: "memory");                           \
  } while (0)

// ---------------------------------------------------------------- CSR
__global__ void count_edges_k(const int* __restrict__ dst, int E, int* __restrict__ cnt) {
  int i = blockIdx.x * blockDim.x + threadIdx.x;
  if (i < E) atomicAdd(&cnt[dst[i]], 1);
}

// exclusive scan via wave shuffles; writes indptr AND cursor
__global__ void scan_k(const int* __restrict__ cnt, int* __restrict__ indptr,
                       int* __restrict__ cursor, int n) {
  __shared__ int wsum[16];
  __shared__ int carry_s;
  const int t = threadIdx.x, lane = t & 63, w = t >> 6;
  if (t == 0) carry_s = 0;
  __syncthreads();
  for (int base = 0; base < n; base += 1024) {
    int i = base + t;
    int v = (i < n) ? cnt[i] : 0;
    int x = v;
#pragma unroll
    for (int off = 1; off < 64; off <<= 1) {
      int y = __shfl_up(x, off);
      if (lane >= off) x += y;
    }
    if (lane == 63) wsum[w] = x;
    __syncthreads();
    if (w == 0 && lane < 16) {
      int y = wsum[lane];
#pragma unroll
      for (int off = 1; off < 16; off <<= 1) {
        int z = __shfl_up(y, off);
        if (lane >= off) y += z;
      }
      wsum[lane] = y;
    }
    __syncthreads();
    int woff = (w == 0) ? 0 : wsum[w - 1];
    int carry = carry_s;
    int incl = x + woff + carry;
    if (i < n) { indptr[i] = incl - v; cursor[i] = incl - v; }
    __syncthreads();
    if (t == 1023) carry_s = incl;
    __syncthreads();
  }
  if (threadIdx.x == 0) indptr[n] = carry_s;
}

__global__ void scatter_k(const int* __restrict__ src, const int* __restrict__ dst, int E, int n,
                          int* __restrict__ cursor, int* __restrict__ esrc) {
  int i = blockIdx.x * blockDim.x + threadIdx.x;
  if (i < E) {
    int p = atomicAdd(&cursor[dst[i]], 1);
    esrc[p] = src[i];
  } else if (i < E + n) {
    int node = i - E;
    int p = atomicAdd(&cursor[node], 1);
    esrc[p] = node;
  }
}

// ---------------------------------------------------------------- merged prep kernel (+init)
__device__ void transpose_dual_body(const float* __restrict__ Wa, int Na,
                                    const float* __restrict__ Wb, int Nb,
                                    int K, ushort_t* __restrict__ dst,
                                    int bxi, int byi, float (*tile)[33]) {
  const int bx = bxi * 32, by = byi * 32;
  const int tx = threadIdx.x & 31, ty = threadIdx.x >> 5;
  const bool isB = bx >= Na;
  const float* W = isB ? Wb : Wa;
  const int Nw = isB ? Nb : Na;
  const int nc = bx - (isB ? Na : 0) + tx;
  for (int i = ty; i < 32; i += 8)
    tile[i][tx] = W[(size_t)(by + i) * Nw + nc];
  __syncthreads();
  for (int i = ty; i < 32; i += 8)
    dst[(size_t)(bx + i) * K + by + tx] = f2bf(tile[tx][i]);
}

__global__ __launch_bounds__(256) void prep_k(const float* __restrict__ x, ushort_t* __restrict__ x_bf, int n4,
                                              const float* __restrict__ W1, const float* __restrict__ l1W, ushort_t* __restrict__ W1cat,
                                              const float* __restrict__ W2, const float* __restrict__ l2W, ushort_t* __restrict__ W2cat,
                                              const float* __restrict__ W3, const float* __restrict__ l3W, ushort_t* __restrict__ W3cat,
                                              const float* __restrict__ a3s, const float* __restrict__ a3d,
                                              int* __restrict__ cursor, int nN, float* __restrict__ z, int nz) {
  __shared__ float tile[32][33];
  const int b = blockIdx.x, t = threadIdx.x;
  if (b < 1250) {
    int i = b * 256 + t;
    if (i < n4) {
      float4 v = ((const float4*)x)[i];
      ushort_t* p = x_bf + i * 4;
      p[0] = f2bf(v.x); p[1] = f2bf(v.y); p[2] = f2bf(v.z); p[3] = f2bf(v.w);
    }
  } else if (b < 1506) {
    int lo = b - 1250;  // (64,4)
    transpose_dual_body(W1, 1024, l1W, 1024, 128, W1cat, lo % 64, lo / 64, tile);
  } else if (b < 3554) {
    int lo = b - 1506;  // (64,32)
    transpose_dual_body(W2, 1024, l2W, 1024, 1024, W2cat, lo % 64, lo / 64, tile);
  } else if (b < 4002) {
    int lo = b - 3554;  // (14,32)
    transpose_dual_body(W3, 384, l3W, 64, 1024, W3cat, lo % 14, lo / 14, tile);
  } else if (b < 4006) {
    int k = (b - 4002) * 256 + t;  // 0..1023
    const float* row = W3 + (size_t)k * 384;
    for (int hd = 0; hd < 6; ++hd) {
      float ss = 0.f, dd = 0.f;
      for (int c = 0; c < 64; ++c) {
        float w = row[hd * 64 + c];
        ss += w * a3s[hd * 64 + c];
        dd += w * a3d[hd * 64 + c];
      }
      W3cat[(size_t)(448 + hd) * 1024 + k] = f2bf(ss);
      W3cat[(size_t)(454 + hd) * 1024 + k] = f2bf(dd);
    }
    for (int j = 460; j < 512; ++j) W3cat[(size_t)j * 1024 + k] = 0;
  } else {
    int i = (b - 4006) * 256 + t;  // init: cursor=1 (self loop), zero logit accumulators
    if (i < nN) cursor[i] = 1;
    if (i < nz) z[i] = 0.f;
  }
}

// ---------------------------------------------------------------- gemm320 v4: 8-wave 5x8 frags
// BM=320 BN=256 BK=64; 512 thr / 8 waves (4 wm x 2 wn); wave tile 80x128, acc[5][8] (160 regs).
// Grid 8x32 = 256 blocks = 1 round. 4-deep half-phase ring: A[4][320][32], B[4][256][32]
// (144 KB); slot swizzle: LDS slot s of row r holds global 16B-slot s^((r>>1)&3).
template<int K, int HC, int SC, bool LOGITS>
__global__ __launch_bounds__(512, 2) void gemm320(const ushort_t* __restrict__ A,
                                                  const ushort_t* __restrict__ BT,
                                                  const float* __restrict__ skip_bias,
                                                  const float* __restrict__ a_src,
                                                  const float* __restrict__ a_dst,
                                                  float* __restrict__ sb,
                                                  float* __restrict__ db,
                                                  ushort_t* __restrict__ h_out,
                                                  ushort_t* __restrict__ skip_out,
                                                  int M) {
  __shared__ ushort_t As[4 * 320 * 32];  // 80 KB
  __shared__ ushort_t Bs[4 * 256 * 32];  // 64 KB
  const int gx = gridDim.x;
  const int nwg = gx * (int)gridDim.y;
  const int orig = blockIdx.y * gx + blockIdx.x;
  const int q = nwg >> 3, r = nwg & 7, xcd = orig & 7;
  const int wgid = (xcd < r ? xcd * (q + 1) : r * (q + 1) + (xcd - r) * q) + (orig >> 3);
  const int bm = (wgid / gx) * 320, bn = (wgid % gx) * 256;

  const int t = threadIdx.x, l = t & 63, wid = t >> 6;
  const bool wlow = (wid < 4);            // waves 0-3: 5 staging loads/phase; 4-7: 4
  const int wm = wid >> 1, wn = wid & 1;  // 4 x 2
  const int lr = l & 15, s4 = l >> 4;

  const int rA0 = t >> 2,          sA0 = (t & 3) ^ ((rA0 >> 1) & 3);
  const int rA1 = (t + 512) >> 2,  sA1 = ((t + 512) & 3) ^ ((rA1 >> 1) & 3);
  const int rA2 = (t + 1024) >> 2, sA2 = ((t + 1024) & 3) ^ ((rA2 >> 1) & 3);
  const size_t gA0 = (size_t)min(bm + rA0, M - 1) * K + sA0 * 8;
  const size_t gA1 = (size_t)min(bm + rA1, M - 1) * K + sA1 * 8;
  const size_t gA2 = (size_t)min(bm + rA2, M - 1) * K + sA2 * 8;
  const size_t gB0 = (size_t)(bn + rA0) * K + sA0 * 8;
  const size_t gB1 = (size_t)(bn + rA1) * K + sA1 * 8;
  const int dA0 = rA0 * 32 + (t & 3) * 8;
  const int dA1 = rA1 * 32 + ((t + 512) & 3) * 8;
  const int dA2 = rA2 * 32 + ((t + 1024) & 3) * 8;

  auto stage_half = [&](int p) {
    const int reg4 = p & 3;
    const int kc = p * 32;
    ushort_t* ar = &As[reg4 * (320 * 32)];
    ushort_t* br = &Bs[reg4 * (256 * 32)];
    gload_lds16(A + gA0 + kc, ar + dA0);
    gload_lds16(A + gA1 + kc, ar + dA1);
    if (t < 256) gload_lds16(A + gA2 + kc, ar + dA2);
    gload_lds16(BT + gB0 + kc, br + dA0);
    gload_lds16(BT + gB1 + kc, br + dA1);
  };

  int offA[5], offB[8];
#pragma unroll
  for (int m = 0; m < 5; ++m) {
    int row = wm * 80 + m * 16 + lr;
    offA[m] = row * 32 + ((s4 ^ ((row >> 1) & 3)) << 3);
  }
#pragma unroll
  for (int n = 0; n < 8; ++n) {
    int row = wn * 128 + n * 16 + lr;
    offB[n] = row * 32 + ((s4 ^ ((row >> 1) & 3)) << 3);
  }

  f32x4 acc[5][8] = {};

  auto body = [&](int p) {
    const int aB = (p & 3) * (320 * 32), bB = (p & 3) * (256 * 32);
    bf16x8 a[5], b[8];
#pragma unroll
    for (int m = 0; m < 5; ++m) a[m] = *(const bf16x8*)&As[aB + offA[m]];
#pragma unroll
    for (int n = 0; n < 8; ++n) b[n] = *(const bf16x8*)&Bs[bB + offB[n]];
    if (p + 3 < (K >> 5)) stage_half(p + 3);
    __builtin_amdgcn_s_setprio(1);
#pragma unroll
    for (int m = 0; m < 5; ++m)
#pragma unroll
      for (int n = 0; n < 8; ++n)
        acc[m][n] = __builtin_amdgcn_mfma_f32_16x16x32_bf16(a[m], b[n], acc[m][n], 0, 0, 0);
    __builtin_amdgcn_s_setprio(0);
  };

  constexpr int NP = K >> 5;
  stage_half(0); stage_half(1); stage_half(2);
  for (int p = 0; p < NP - 2; ++p) {
    WAITC(10, 8);
    body(p);
  }
  WAITC(5, 4); body(NP - 2);
  WAITC(0, 0); body(NP - 1);

  // ---- fused logits (L1/L2): wave's 128 cols lie within one 256-col head
  if (LOGITS && bn < HC) {
    const int head = bn >> 8;
    float as[8], ad[8];
#pragma unroll
    for (int n = 0; n < 8; ++n) {
      int c = (bn + wn * 128 + n * 16 + lr) & 255;
      as[n] = a_src[head * 256 + c];
      ad[n] = a_dst[head * 256 + c];
    }
#pragma unroll
    for (int mi = 0; mi < 5; ++mi) {
#pragma unroll
      for (int j = 0; j < 4; ++j) {
        float sp = 0.f, dp = 0.f;
#pragma unroll
        for (int n = 0; n < 8; ++n) { sp += acc[mi][n][j] * as[n]; dp += acc[mi][n][j] * ad[n]; }
#pragma unroll
        for (int off = 1; off <= 8; off <<= 1) {
          sp += __shfl_xor(sp, off);
          dp += __shfl_xor(dp, off);
        }
        if (lr == 0) {
          int row = bm + wm * 80 + mi * 16 + s4 * 4 + j;
          if (row < M) {
            atomicAdd(&sb[row * 4 + head], sp);
            atomicAdd(&db[row * 4 + head], dp);
          }
        }
      }
    }
  }

  // ---- epilogue: LDS transpose (padded) -> coalesced 32B row stores (2 passes of 32 rows)
  constexpr int EPS = 264;
  ushort_t* EP = As;
  const bool isH = (bn < HC);
#pragma unroll
  for (int mi = 0; mi < 5; ++mi) {
    __syncthreads();
#pragma unroll
    for (int n = 0; n < 8; ++n) {
      float bvn = isH ? 0.f : skip_bias[bn - HC + wn * 128 + n * 16 + lr];
#pragma unroll
      for (int j = 0; j < 4; ++j)
        EP[(wm * 16 + s4 * 4 + j) * EPS + wn * 128 + n * 16 + lr] = f2bf(acc[mi][n][j] + bvn);
    }
    __syncthreads();
#pragma unroll
    for (int rep = 0; rep < 2; ++rep) {
      const int r_l = (t >> 4) + rep * 32;
      const int c0 = (t & 15) * 16;
      const int grow = bm + (r_l >> 4) * 80 + mi * 16 + (r_l & 15);
      if (grow < M) {
        const ushort_t* srcp = &EP[r_l * EPS + c0];
        ushort_t* dst = isH ? &h_out[(size_t)grow * HC + bn + c0]
                            : &skip_out[(size_t)grow * SC + (bn - HC) + c0];
        *(uint4*)dst = *(const uint4*)srcp;
        *(uint4*)(dst + 8) = *(const uint4*)(srcp + 8);
      }
    }
  }
}

// ---------------------------------------------------------------- 128x128 ring GEMM (L3)
template<int NCT, int HC, int SC, bool SD_COLS>
__global__ __launch_bounds__(256) void gemm_fused(const ushort_t* __restrict__ A,
                                                  const ushort_t* __restrict__ BT,
                                                  const float* __restrict__ skip_bias,
                                                  float* __restrict__ sb,
                                                  float* __restrict__ db,
                                                  ushort_t* __restrict__ h_out,
                                                  float* __restrict__ skip_out,
                                                  int M, int K) {
  __shared__ ushort_t As[4][128 * 32];
  __shared__ ushort_t Bs[4][128 * 32];
  const int gx = gridDim.x;
  const int nwg = gx * (int)gridDim.y;
  const int orig = blockIdx.y * gx + blockIdx.x;
  const int q = nwg >> 3, r = nwg & 7, xcd = orig & 7;
  const int wgid = (xcd < r ? xcd * (q + 1) : r * (q + 1) + (xcd - r) * q) + (orig >> 3);
  const int bm = (wgid / gx) * 128, bn = (wgid % gx) * 128;

  const int t = threadIdx.x;
  const int l = t & 63, wid = t >> 6;
  const int wm = wid >> 1, wn = wid & 1;

  size_t goffA[2], goffB[2];
  for (int i = 0; i < 2; ++i) {
    int seg = wid * 2 + i;
    int row = seg * 16 + (l >> 2);
    int p = l & 3;
    int ls = p ^ ((row >> 1) & 3);
    int ga = min(bm + row, M - 1);
    int gb = min(bn + row, NCT - 1);
    goffA[i] = (size_t)ga * K + ls * 8;
    goffB[i] = (size_t)gb * K + ls * 8;
  }

  const int lr = l & 15, s = l >> 4;
  int raddrA[4], raddrB[4];
  for (int m = 0; m < 4; ++m) {
    int rowA = wm * 64 + m * 16 + lr;
    raddrA[m] = rowA * 32 + (s ^ ((rowA >> 1) & 3)) * 8;
    int rowB = wn * 64 + m * 16 + lr;
    raddrB[m] = rowB * 32 + (s ^ ((rowB >> 1) & 3)) * 8;
  }

  f32x4 acc[4][4] = {};
  auto stage = [&](int st) {
    int buf = st & 3;
    int k0 = st * 32;
    gload_lds16(A + goffA[0] + k0, &As[buf][(wid * 2 + 0) * 512]);
    gload_lds16(A + goffA[1] + k0, &As[buf][(wid * 2 + 1) * 512]);
    gload_lds16(BT + goffB[0] + k0, &Bs[buf][(wid * 2 + 0) * 512]);
    gload_lds16(BT + goffB[1] + k0, &Bs[buf][(wid * 2 + 1) * 512]);
  };
  auto body = [&](int st) {
    int buf = st & 3;
    bf16x8 a[4], b[4];
#pragma unroll
    for (int m = 0; m < 4; ++m) a[m] = *(const bf16x8*)&As[buf][raddrA[m]];
#pragma unroll
    for (int n = 0; n < 4; ++n) b[n] = *(const bf16x8*)&Bs[buf][raddrB[n]];
#pragma unroll
    for (int m = 0; m < 4; ++m)
#pragma unroll
      for (int n = 0; n < 4; ++n)
        acc[m][n] = __builtin_amdgcn_mfma_f32_16x16x32_bf16(a[m], b[n], acc[m][n], 0, 0, 0);
  };

  const int T = K >> 5;
  stage(0); stage(1); stage(2);
  int st = 0;
  for (; st < T - 3; ++st) {
    PIPE_BAR(8);
    body(st);
    stage(st + 3);
  }
  PIPE_BAR(8); body(T - 3);
  PIPE_BAR(4); body(T - 2);
  PIPE_BAR(0); body(T - 1);

#pragma unroll
  for (int n = 0; n < 4; ++n) {
    int col = bn + wn * 64 + n * 16 + lr;
    if (col >= HC + SC + (SD_COLS ? 12 : 0)) continue;
    const bool is_h = col < HC;
    const bool is_skip = !is_h && col < HC + SC;
    float bv = is_skip ? skip_bias[col - HC] : 0.f;
#pragma unroll
    for (int m = 0; m < 4; ++m) {
#pragma unroll
      for (int j = 0; j < 4; ++j) {
        int row = bm + wm * 64 + m * 16 + (l >> 4) * 4 + j;
        if (row >= M) continue;
        float v = acc[m][n][j] + bv;
        if (is_h) {
          h_out[(size_t)row * HC + col] = f2bf(v);
        } else if (is_skip) {
          skip_out[(size_t)row * SC + (col - HC)] = v;
        } else if (SD_COLS) {
          int jj = col - (HC + SC);
          if (jj < 6) sb[row * 6 + jj] = v;
          else        db[row * 6 + (jj - 6)] = v;
        }
      }
    }
  }
}

// ---------------------------------------------------------------- attn L1/L2: parity-split gather
template<bool ELU_OUT>
__global__ __launch_bounds__(256) void attn4_k(const ushort_t* __restrict__ hfeat,
                                               const float* __restrict__ sbuf,
                                               const float* __restrict__ dbuf,
                                               const int* __restrict__ indptr,
                                               const int* __restrict__ esrc,
                                               const float* __restrict__ bias,
                                               const ushort_t* __restrict__ skip,
                                               ushort_t* __restrict__ out) {
  constexpr int H = 4, F = 1024, CH = 64;
  __shared__ float m_l[H], invden_l[H], d_l[H];
  __shared__ float alpha_l[CH * H];
  __shared__ int src_l[CH];
  __shared__ float mrg[F];  // 4 KB parity-merge buffer

  const int node = blockIdx.x;
  const int t = threadIdx.x;
  const int beg = indptr[node];
  const int deg = indptr[node + 1] - beg;
  if (t < H) d_l[t] = dbuf[node * H + t];
  __syncthreads();

  const int wave = t >> 6, lane = t & 63;
  {
    const int hd = wave;
    const float dn = d_l[hd];
    float mx = -1e30f;
    for (int i = lane; i < deg; i += 64) {
      float e = sbuf[esrc[beg + i] * H + hd] + dn;
      e = fmaxf(e, 0.2f * e);
      mx = fmaxf(mx, e);
    }
    for (int off = 32; off; off >>= 1) mx = fmaxf(mx, __shfl_xor(mx, off));
    float den = 0.f;
    for (int i = lane; i < deg; i += 64) {
      float e = sbuf[esrc[beg + i] * H + hd] + dn;
      e = fmaxf(e, 0.2f * e);
      den += __expf(e - mx);
    }
    for (int off = 32; off; off >>= 1) den += __shfl_xor(den, off);
    if (lane == 0) { m_l[hd] = mx; invden_l[hd] = 1.f / den; }
  }
  __syncthreads();

  const int eo = t >> 7;
  const int tc = t & 127;
  const int c0 = tc * 8;
  const int myhead = tc >> 5;
  float acc[8] = {};
  for (int cb = 0; cb < deg; cb += CH) {
    const int ce = min(CH, deg - cb);
    if (t < ce * H) {
      int e_i = t >> 2, hd = t & 3;
      int se = esrc[beg + cb + e_i];
      if (hd == 0) src_l[e_i] = se;
      float e = sbuf[se * H + hd] + d_l[hd];
      e = fmaxf(e, 0.2f * e);
      alpha_l[e_i * H + hd] = __expf(e - m_l[hd]) * invden_l[hd];
    }
    __syncthreads();
    for (int e_i = eo; e_i < ce; e_i += 2) {
      int se = src_l[e_i];
      float al = alpha_l[e_i * H + myhead];
      uint4 v = *(const uint4*)(hfeat + (size_t)se * F + c0);
      acc[0] += al * bflo(v.x); acc[1] += al * bfhi(v.x);
      acc[2] += al * bflo(v.y); acc[3] += al * bfhi(v.y);
      acc[4] += al * bflo(v.z); acc[5] += al * bfhi(v.z);
      acc[6] += al * bflo(v.w); acc[7] += al * bfhi(v.w);
    }
    __syncthreads();
  }

  if (eo == 1) {
#pragma unroll
    for (int j = 0; j < 8; ++j) mrg[c0 + j] = acc[j];
  }
  __syncthreads();
  if (eo == 0) {
    uint4 sv = *(const uint4*)&skip[(size_t)node * F + c0];
    float sk[8] = {bflo(sv.x), bfhi(sv.x), bflo(sv.y), bfhi(sv.y),
                   bflo(sv.z), bfhi(sv.z), bflo(sv.w), bfhi(sv.w)};
    unsigned w[4];
#pragma unroll
    for (int p = 0; p < 4; ++p) {
      float x0 = acc[2 * p] + mrg[c0 + 2 * p] + bias[c0 + 2 * p] + sk[2 * p];
      float x1 = acc[2 * p + 1] + mrg[c0 + 2 * p + 1] + bias[c0 + 2 * p + 1] + sk[2 * p + 1];
      if (ELU_OUT) {
        x0 = x0 > 0.f ? x0 : __expf(x0) - 1.f;
        x1 = x1 > 0.f ? x1 : __expf(x1) - 1.f;
      }
      w[p] = (unsigned)f2bf(x0) | ((unsigned)f2bf(x1) << 16);
    }
    uint4 o; o.x = w[0]; o.y = w[1]; o.z = w[2]; o.w = w[3];
    *(uint4*)&out[(size_t)node * F + c0] = o;
  }
}

// ---------------------------------------------------------------- attn L3 (H=6, C=64, mean-heads)
template<int H, int C>
__global__ __launch_bounds__(256) void attn_mean_k(const ushort_t* __restrict__ hfeat,
                                                   const float* __restrict__ sbuf,
                                                   const float* __restrict__ dbuf,
                                                   const int* __restrict__ indptr,
                                                   const int* __restrict__ esrc,
                                                   const float* __restrict__ bias,
                                                   const float* __restrict__ skip,
                                                   float* __restrict__ out) {
  constexpr int F = H * C;
  constexpr int CPT = 2;
  constexpr int CH = 256 / H;
  __shared__ float m_l[H], invden_l[H], d_l[H];
  __shared__ float alpha_l[CH * H];
  __shared__ int src_l[CH];
  __shared__ float accs[F];

  const int node = blockIdx.x;
  const int t = threadIdx.x;
  const int beg = indptr[node];
  const int deg = indptr[node + 1] - beg;
  if (t < H) d_l[t] = dbuf[node * H + t];
  __syncthreads();

  const int wave = t >> 6, lane = t & 63;
  for (int hd = wave; hd < H; hd += 4) {
    const float dn = d_l[hd];
    float mx = -1e30f;
    for (int i = lane; i < deg; i += 64) {
      float e = sbuf[esrc[beg + i] * H + hd] + dn;
      e = fmaxf(e, 0.2f * e);
      mx = fmaxf(mx, e);
    }
    for (int off = 32; off; off >>= 1) mx = fmaxf(mx, __shfl_xor(mx, off));
    float den = 0.f;
    for (int i = lane; i < deg; i += 64) {
      float e = sbuf[esrc[beg + i] * H + hd] + dn;
      e = fmaxf(e, 0.2f * e);
      den += __expf(e - mx);
    }
    for (int off = 32; off; off >>= 1) den += __shfl_xor(den, off);
    if (lane == 0) { m_l[hd] = mx; invden_l[hd] = 1.f / den; }
  }
  __syncthreads();

  float acc[CPT] = {};
  const int c0 = t * CPT;
  const int myhead = c0 / C;
  for (int cb = 0; cb < deg; cb += CH) {
    const int ce = min(CH, deg - cb);
    if (t < ce * H) {
      int e_i = t / H, hd = t % H;
      int se = esrc[beg + cb + e_i];
      if (hd == 0) src_l[e_i] = se;
      float e = sbuf[se * H + hd] + d_l[hd];
      e = fmaxf(e, 0.2f * e);
      alpha_l[e_i * H + hd] = __expf(e - m_l[hd]) * invden_l[hd];
    }
    __syncthreads();
    if (c0 < F) {
      for (int e_i = 0; e_i < ce; ++e_i) {
        int se = src_l[e_i];
        float al = alpha_l[e_i * H + myhead];
        ushort2 v = *(const ushort2*)(hfeat + (size_t)se * F + c0);
        acc[0] += al * bf2f(v.x); acc[1] += al * bf2f(v.y);
      }
    }
    __syncthreads();
  }

  if (c0 < F) { accs[c0] = acc[0]; accs[c0 + 1] = acc[1]; }
  __syncthreads();
  if (t < C) {
    float sum = 0.f;
#pragma unroll
    for (int hd = 0; hd < H; ++hd) sum += accs[hd * C + t];
    out[(size_t)node * C + t] = sum * (1.f / (float)H) + bias[t] + skip[(size_t)node * C + t];
  }
}

// ---------------------------------------------------------------- launch
extern "C" void kernel_launch(void* const* d_in, const int* in_sizes, int n_in,
                              void* d_out, int out_size, void* d_ws, size_t ws_size,
                              hipStream_t stream) {
  const float* x      = (const float*)d_in[0];
  const int*   ei     = (const int*)d_in[1];
  const float* W1     = (const float*)d_in[2];
  const float* a1s    = (const float*)d_in[3];
  const float* a1d    = (const float*)d_in[4];
  const float* b1     = (const float*)d_in[5];
  const float* lin1W  = (const float*)d_in[6];
  const float* lin1b  = (const float*)d_in[7];
  const float* W2     = (const float*)d_in[8];
  const float* a2s    = (const float*)d_in[9];
  const float* a2d    = (const float*)d_in[10];
  const float* b2     = (const float*)d_in[11];
  const float* lin2W  = (const float*)d_in[12];
  const float* lin2b  = (const float*)d_in[13];
  const float* W3     = (const float*)d_in[14];
  const float* a3s    = (const float*)d_in[15];
  const float* a3d    = (const float*)d_in[16];
  const float* b3     = (const float*)d_in[17];
  const float* lin3W  = (const float*)d_in[18];
  const float* lin3b  = (const float*)d_in[19];

  const int N = in_sizes[0] / 128;
  const int E = in_sizes[1] / 2;
  const int* src = ei;
  const int* dst = ei + E;

  char* ws = (char*)d_ws;
  size_t off = 0;
  auto alloc = [&](size_t bytes) -> void* {
    void* p = ws + off;
    off += (bytes + 255) & ~(size_t)255;
    return p;
  };
  ushort_t* h_bf    = (ushort_t*)alloc((size_t)N * 1024 * 2);
  ushort_t* skip_bf = (ushort_t*)alloc((size_t)N * 1024 * 2);
  float*    skip3   = (float*)alloc((size_t)N * 64 * 4);
  ushort_t* act_bf  = (ushort_t*)alloc((size_t)N * 1024 * 2);
  ushort_t* x_bf    = (ushort_t*)alloc((size_t)N * 128 * 2);
  ushort_t* W1cat   = (ushort_t*)alloc((size_t)2048 * 128 * 2);
  ushort_t* W2cat   = (ushort_t*)alloc((size_t)2048 * 1024 * 2);
  ushort_t* W3cat   = (ushort_t*)alloc((size_t)512 * 1024 * 2);
  float*    sd12    = (float*)alloc((size_t)4 * N * 4 * 4);
  float*    sb1 = sd12, *db1 = sd12 + N * 4, *sb2 = sd12 + 2 * N * 4, *db2 = sd12 + 3 * N * 4;
  float*    sb3     = (float*)alloc((size_t)N * 6 * 4);
  float*    db3     = (float*)alloc((size_t)N * 6 * 4);
  int*      indptr  = (int*)alloc((size_t)(N + 1) * 4);
  int*      cursor  = (int*)alloc((size_t)N * 4);
  int*      esrc    = (int*)alloc((size_t)(E + N) * 4);

  const int n4 = N * 128 / 4;
  const int NZ = 4 * N * 4;
  const int initBlocks = (max(N, NZ) + 255) / 256;
  prep_k<<<4006 + initBlocks, 256, 0, stream>>>(x, x_bf, n4, W1, lin1W, W1cat, W2, lin2W, W2cat,
                                                W3, lin3W, W3cat, a3s, a3d, cursor, N, sd12, NZ);

  count_edges_k<<<(E + 255) / 256, 256, 0, stream>>>(dst, E, cursor);
  scan_k<<<1, 1024, 0, stream>>>(cursor, indptr, cursor, N);
  scatter_k<<<(E + N + 255) / 256, 256, 0, stream>>>(src, dst, E, N, cursor, esrc);

  const int MB  = (N + 127) / 128;
  const int MB3 = (N + 319) / 320;
  // ---- Layer 1 (K=128)
  gemm320<128, 1024, 1024, true><<<dim3(8, MB3), 512, 0, stream>>>(
      x_bf, W1cat, lin1b, a1s, a1d, sb1, db1, h_bf, skip_bf, N);
  attn4_k<true><<<N, 256, 0, stream>>>(h_bf, sb1, db1, indptr, esrc, b1, skip_bf, act_bf);
  // ---- Layer 2 (K=1024)
  gemm320<1024, 1024, 1024, true><<<dim3(8, MB3), 512, 0, stream>>>(
      act_bf, W2cat, lin2b, a2s, a2d, sb2, db2, h_bf, skip_bf, N);
  attn4_k<true><<<N, 256, 0, stream>>>(h_bf, sb2, db2, indptr, esrc, b2, skip_bf, act_bf);
  // ---- Layer 3 (128x128 ring; logits via folded cols 448..459)
  gemm_fused<512, 384, 64, true><<<dim3(4, MB), 256, 0, stream>>>(
      act_bf, W3cat, lin3b, sb3, db3, h_bf, skip3, N, 1024);
  attn_mean_k<6, 64><<<N, 256, 0, stream>>>(h_bf, sb3, db3, indptr, esrc, b3, skip3, (float*)d_out);
}